// Round 14
// baseline (1025.304 us; speedup 1.0000x reference)
//
#include <hip/hip_runtime.h>
#include <hip/hip_bf16.h>

// CktGNN encoder via MFMA. R14: global_load_lds B-streaming.
// R13 lesson: register-staged B caps at ~19-24 B/cyc/block (in-flight bytes
// limited by the register file; congestion latency ~1-4k cyc). R10 proved the
// CU path does ~49 B/cyc with more independent streams. Fix: DMA B into a
// per-wave 9KB LDS ring via __builtin_amdgcn_global_load_lds (zero VGPR cost,
// deep in-flight), counted vmcnt waits (never 0 mid-stream), sched_barrier(0)
// fences (rule 18), batched epilogues to keep vmcnt accounting pure, and
// cross-barrier prologue issues. NTH=256, BT=16, grid=256, sorted groups.
//   GRU ext K=352: [Hin(301) | onehot_t(26) | onehot_p(9) | 1 | pad]
//   gate ext K=320: [H(301) | onehot_p(9) | 1 | pad]
// B padded to NJT=20 j-tiles (tile 19 = zeros) so every wave runs a uniform
// 5-tile stream (w + 4r, r=0..4).

#define HS 301
#define NVT 26
#define MAXPOS 9
#define MAXN 10
#define BSZ 4096
#define VS 310
#define GS 309
#define NZ 56

#define KT1 11          // GRU ext K tiles (K=352)
#define KT2 10          // gate ext K tiles (K=320)
#define NJT 20          // j tiles incl. zero-pad tile 19
#define NB1 (NJT*KT1*3*512)   // f16 count = 337920
#define NB2 (NJT*KT2*2*512)   // f16 count = 204800

typedef _Float16 f16x8 __attribute__((ext_vector_type(8)));
typedef float f32x4 __attribute__((ext_vector_type(4)));

constexpr int NTH  = 256;    // 4 waves
constexpr int BT   = 16;
constexpr int NBLK = 256;

__device__ __forceinline__ int fragOff(int g, int k) {
  return ((k >> 5) << 10) + ((((k & 31) >> 3) << 4) + g) * 16 + ((k & 7) << 1);
}
__device__ __forceinline__ float sigm(float x) { return 1.0f / (1.0f + __expf(-x)); }
__device__ __forceinline__ float tanh_fast(float x) {
  float e = __expf(2.0f * x);
  return 1.0f - 2.0f / (e + 1.0f);
}
// Raw barrier: drain LDS ops only; DMA (vmcnt) stays in flight.
#define BAR() { asm volatile("s_waitcnt lgkmcnt(0)" ::: "memory"); \
                __builtin_amdgcn_s_barrier(); }
#define GLDS(GP, LP) __builtin_amdgcn_global_load_lds( \
    (const __attribute__((address_space(1))) void*)(GP), \
    (__attribute__((address_space(3))) void*)(LP), 16, 0, 0)

// ---------------- sort: counting sort graphs by depth n ----------------
__global__ void ckt_sort(const int* __restrict__ vcount, int* __restrict__ order) {
  __shared__ int cnt[12], off[12];
  int tid = threadIdx.x;
  if (tid < 12) cnt[tid] = 0;
  __syncthreads();
  for (int g = tid; g < BSZ; g += 1024) {
    int n = vcount[g]; n = n < 1 ? 1 : (n > MAXN ? MAXN : n);
    atomicAdd(&cnt[n], 1);
  }
  __syncthreads();
  if (tid == 0) {
    int s = 0;
    for (int i = 1; i <= MAXN; ++i) { off[i] = s; s += cnt[i]; }
  }
  __syncthreads();
  for (int g = tid; g < BSZ; g += 1024) {
    int n = vcount[g]; n = n < 1 ? 1 : (n > MAXN ? MAXN : n);
    int p = atomicAdd(&off[n], 1);
    order[p] = g;
  }
}

// ---------------- prep: pack weights into fragment order ----------------
__global__ void ckt_prep(const float* __restrict__ Wih, const float* __restrict__ Whh,
                         const float* __restrict__ b_ih, const float* __restrict__ b_hh,
                         const float* __restrict__ Wg,  const float* __restrict__ bg,
                         const float* __restrict__ Wm,
                         const float* __restrict__ Wmu, const float* __restrict__ Wlv,
                         unsigned short* __restrict__ B1, unsigned short* __restrict__ B2,
                         float* __restrict__ WnX, float* __restrict__ bn,
                         float* __restrict__ WmuT, float* __restrict__ WlvT)
{
  int i0 = blockIdx.x * blockDim.x + threadIdx.x;
  int str = gridDim.x * blockDim.x;
  // B1: [jt][kt][g3][lane][ii]
  for (int i = i0; i < NB1; i += str) {
    int ii = i & 7, lane = (i >> 3) & 63;
    int r = i >> 9;
    int g3 = r % 3; r /= 3;
    int kt = r % KT1; int jt = r / KT1;
    int j = jt * 16 + (lane & 15);
    int k = kt * 32 + ((lane >> 4) << 3) + ii;
    float val = 0.f;
    if (j < HS) {
      int row = g3 * HS + j;
      if (k < HS) val = Whh[row * HS + k];
      else if (k == 336) val = (g3 < 2) ? (b_ih[row] + b_hh[row]) : b_hh[row];
      else if (g3 < 2) {
        if (k < 327)      val = Wih[row * 35 + (k - 301)];
        else if (k < 336) val = Wih[row * 35 + 26 + (k - 327)];
      }
    }
    B1[i] = __builtin_bit_cast(unsigned short, (_Float16)val);
  }
  // B2: [jt][kt][gm][lane][ii]
  for (int i = i0; i < NB2; i += str) {
    int ii = i & 7, lane = (i >> 3) & 63;
    int r = i >> 9;
    int gm = r % 2; r /= 2;
    int kt = r % KT2; int jt = r / KT2;
    int j = jt * 16 + (lane & 15);
    int k = kt * 32 + ((lane >> 4) << 3) + ii;
    float val = 0.f;
    if (j < HS) {
      const float* W = gm ? Wm : Wg;
      if (k < HS)       val = W[j * VS + k];
      else if (k < 310) val = W[j * VS + HS + (k - 301)];
      else if (k == 310) val = gm ? 0.f : bg[j];
    }
    B2[i] = __builtin_bit_cast(unsigned short, (_Float16)val);
  }
  for (int i = i0; i < 35 * 320; i += str) {
    int x = i / 320, j = i % 320;
    WnX[i] = (j < HS) ? Wih[(2 * HS + j) * 35 + x] : 0.f;
  }
  for (int i = i0; i < 320; i += str) bn[i] = (i < HS) ? b_ih[2 * HS + i] : 0.f;
  for (int i = i0; i < GS * NZ; i += str) {
    int k = i / NZ, o = i % NZ;
    WmuT[i] = Wmu[o * GS + k];
    WlvT[i] = Wlv[o * GS + k];
  }
}

// ---------------- main ----------------
__global__ __launch_bounds__(NTH, 1) void ckt_main(
    const int* __restrict__ node_type, const int* __restrict__ pos,
    const int* __restrict__ adj, const int* __restrict__ vcount,
    const float* __restrict__ rin, const float* __restrict__ cin,
    const float* __restrict__ gmin,
    const float* __restrict__ W1, const float* __restrict__ b1,
    const float* __restrict__ W2, const float* __restrict__ b2,
    const float* __restrict__ bmu, const float* __restrict__ blv,
    const char* __restrict__ B1, const char* __restrict__ B2,
    const float* __restrict__ WnX, const float* __restrict__ bnG,
    const float* __restrict__ WmuT, const float* __restrict__ WlvT,
    const int* __restrict__ order,
    float* __restrict__ out)
{
  __shared__ __align__(16) _Float16 sGhist[9 * 16 * 304]; // 87.5 KB
  __shared__ __align__(16) char sAf1[KT1 * 1024];         // 11 KB
  __shared__ __align__(16) char sAf2[KT2 * 1024];         // 10 KB
  __shared__ __align__(16) _Float16 sHg[16 * 304];        // 9.5 KB
  __shared__ __align__(16) char sStageC[4 * 9216];        // 36 KB DMA rings
  __shared__ float sBn[320];
  __shared__ int s_gi[16];
  __shared__ int s_t[160], s_p[160], s_n[16];
  __shared__ unsigned s_am[160];
  __shared__ int s_nmax;
  // post-loop overlays onto sStageC (no DMA outstanding after the v-loop)
  float (*s_df)[28] = (float (*)[28])(sStageC);
  float (*s_hd)[16] = (float (*)[16])(sStageC + 2048);
  float (*s_hd2)[8] = (float (*)[8])(sStageC + 4096);

  const int tid  = threadIdx.x;
  const int b0   = blockIdx.x * BT;
  const int w    = tid >> 6;          // 0..3
  const int lane = tid & 63;
  char* stW = sStageC + w * 9216;     // this wave's 9-slot ring

  if (tid < 16) s_gi[tid] = order[b0 + tid];
  __syncthreads();
  if (tid < 16) {
    int n = vcount[s_gi[tid]];
    s_n[tid] = n < 1 ? 1 : (n > MAXN ? MAXN : n);
    sHg[tid * 304 + 301] = (_Float16)0.f;
    sHg[tid * 304 + 302] = (_Float16)0.f;
    sHg[tid * 304 + 303] = (_Float16)0.f;
  }
  if (tid < 160) {
    int g = tid / 10, vv = tid % 10;
    s_t[tid] = node_type[s_gi[g] * MAXN + vv];
    s_p[tid] = pos[s_gi[g] * MAXN + vv];
  }
  for (int k = tid; k < 320; k += NTH) sBn[k] = bnG[k];
  __syncthreads();
  if (tid < 160) {
    int g = tid / 10, vv = tid % 10;
    unsigned m = 0;
    if (vv < s_n[g]) {
      for (int u = 0; u < vv; ++u)
        if (adj[s_gi[g] * 100 + u * 10 + vv]) m |= (1u << u);
    }
    s_am[tid] = m;
  }
  if (tid == 0) {
    int mx = 1;
    for (int g = 0; g < 16; ++g) mx = max(mx, s_n[g]);
    s_nmax = mx;
  }
  __syncthreads();
  const int nmax = s_nmax;

  const int lq4 = (lane >> 4) << 2;
  const int jc  = lane & 15;

  // ---- DMA issue macros (group = all chunks of one kt of one tile) ----
#define G_ISS(G) { \
    const char* gp = B1 + ((((size_t)(w + 4 * ((G) / 11)) * 11 + ((G) % 11)) * 3) << 10) + ((size_t)lane << 4); \
    char* lp = stW + ((((G) % 3) * 3) << 10); \
    GLDS(gp, lp); GLDS(gp + 1024, lp + 1024); GLDS(gp + 2048, lp + 2048); }
#define Q_ISS(G) { \
    const char* gp = B2 + ((((size_t)(w + 4 * ((G) / 10)) * 10 + ((G) % 10)) * 2) << 10) + ((size_t)lane << 4); \
    char* lp = stW + ((((G) % 3) * 2) << 10); \
    GLDS(gp, lp); GLDS(gp + 1024, lp + 1024); }

  // ---- stream stage macros ----
#define G_STG(G, A0, A1, A2, NW) { \
    asm volatile("s_waitcnt vmcnt(%0)" :: "i"(NW) : "memory"); \
    __builtin_amdgcn_sched_barrier(0); \
    f16x8 av = *(const f16x8*)(sAf1 + (((G) % 11) << 10) + (lane << 4)); \
    f16x8 b0 = *(const f16x8*)(stW + ((((G) % 3) * 3 + 0) << 10) + (lane << 4)); \
    f16x8 b1 = *(const f16x8*)(stW + ((((G) % 3) * 3 + 1) << 10) + (lane << 4)); \
    f16x8 b2 = *(const f16x8*)(stW + ((((G) % 3) * 3 + 2) << 10) + (lane << 4)); \
    A0 = __builtin_amdgcn_mfma_f32_16x16x32_f16(av, b0, A0, 0, 0, 0); \
    A1 = __builtin_amdgcn_mfma_f32_16x16x32_f16(av, b1, A1, 0, 0, 0); \
    A2 = __builtin_amdgcn_mfma_f32_16x16x32_f16(av, b2, A2, 0, 0, 0); \
    if ((G) + 3 < 55) G_ISS((G) + 3); }
#define Q_STG(G, C0, C1, NW) { \
    asm volatile("s_waitcnt vmcnt(%0)" :: "i"(NW) : "memory"); \
    __builtin_amdgcn_sched_barrier(0); \
    f16x8 av = *(const f16x8*)(sAf2 + (((G) % 10) << 10) + (lane << 4)); \
    f16x8 b0 = *(const f16x8*)(stW + ((((G) % 3) * 2 + 0) << 10) + (lane << 4)); \
    f16x8 b1 = *(const f16x8*)(stW + ((((G) % 3) * 2 + 1) << 10) + (lane << 4)); \
    C0 = __builtin_amdgcn_mfma_f32_16x16x32_f16(av, b0, C0, 0, 0, 0); \
    C1 = __builtin_amdgcn_mfma_f32_16x16x32_f16(av, b1, C1, 0, 0, 0); \
    if ((G) + 3 < 50) Q_ISS((G) + 3); }

#define G_T11(A0, A1, A2, B) \
    G_STG((B)+0,A0,A1,A2,6) G_STG((B)+1,A0,A1,A2,6) G_STG((B)+2,A0,A1,A2,6) \
    G_STG((B)+3,A0,A1,A2,6) G_STG((B)+4,A0,A1,A2,6) G_STG((B)+5,A0,A1,A2,6) \
    G_STG((B)+6,A0,A1,A2,6) G_STG((B)+7,A0,A1,A2,6) G_STG((B)+8,A0,A1,A2,6) \
    G_STG((B)+9,A0,A1,A2,6) G_STG((B)+10,A0,A1,A2,6)
#define G_T11L(A0, A1, A2, B) \
    G_STG((B)+0,A0,A1,A2,6) G_STG((B)+1,A0,A1,A2,6) G_STG((B)+2,A0,A1,A2,6) \
    G_STG((B)+3,A0,A1,A2,6) G_STG((B)+4,A0,A1,A2,6) G_STG((B)+5,A0,A1,A2,6) \
    G_STG((B)+6,A0,A1,A2,6) G_STG((B)+7,A0,A1,A2,6) G_STG((B)+8,A0,A1,A2,6) \
    G_STG((B)+9,A0,A1,A2,3) G_STG((B)+10,A0,A1,A2,0)
#define Q_T10(C0, C1, B) \
    Q_STG((B)+0,C0,C1,4) Q_STG((B)+1,C0,C1,4) Q_STG((B)+2,C0,C1,4) \
    Q_STG((B)+3,C0,C1,4) Q_STG((B)+4,C0,C1,4) Q_STG((B)+5,C0,C1,4) \
    Q_STG((B)+6,C0,C1,4) Q_STG((B)+7,C0,C1,4) Q_STG((B)+8,C0,C1,4) \
    Q_STG((B)+9,C0,C1,4)
#define Q_T10L(C0, C1, B) \
    Q_STG((B)+0,C0,C1,4) Q_STG((B)+1,C0,C1,4) Q_STG((B)+2,C0,C1,4) \
    Q_STG((B)+3,C0,C1,4) Q_STG((B)+4,C0,C1,4) Q_STG((B)+5,C0,C1,4) \
    Q_STG((B)+6,C0,C1,4) Q_STG((B)+7,C0,C1,4) Q_STG((B)+8,C0,C1,2) \
    Q_STG((B)+9,C0,C1,0)

#define GRU_EPI(R, A0, A1, A2) { \
    int j = (w + 4 * (R)) * 16 + jc; \
    bool jv = j < HS; \
    _Pragma("unroll") \
    for (int q = 0; q < 4; ++q) { \
      int g = lq4 + q; \
      float inn = 0.f; \
      if (jv) { \
        int t = s_t[g * 10 + v], p = s_p[g * 10 + v]; \
        inn = sBn[j] + WnX[t * 320 + j] + WnX[(26 + p) * 320 + j]; \
      } \
      float rg = sigm(A0[q]); \
      float zg = sigm(A1[q]); \
      float ng = tanh_fast(inn + rg * A2[q]); \
      float hinv = jv ? (float)*(const _Float16*)(sAf1 + fragOff(g, j)) : 0.f; \
      float hv = (1.f - zg) * ng + zg * hinv; \
      float hval = (v < s_n[g]) ? hv : 0.f; \
      if (jv) { \
        *(_Float16*)(sAf2 + fragOff(g, j)) = (_Float16)hval; \
        if (v == s_n[g] - 1) sHg[g * 304 + j] = (_Float16)hv; \
      } \
    } }
#define GATE_EPI(R, C0, C1) { \
    int j = (w + 4 * (R)) * 16 + jc; \
    if (j < HS) { \
      _Pragma("unroll") \
      for (int q = 0; q < 4; ++q) { \
        int g = lq4 + q; \
        float gg = sigm(C0[q]); \
        sGhist[(v * 16 + g) * 304 + j] = (_Float16)(gg * C1[q]); \
      } \
    } }

  // initial GRU prologue (flies through phase A of v=0)
  G_ISS(0) G_ISS(1) G_ISS(2)

  for (int v = 0; v < nmax; ++v) {
    // ---------- phase A (LDS-only): GRU A-frags + gate one-hots ----------
    for (int c = tid; c < KT1 * 64; c += NTH) {
      int kt = c >> 6, ln = c & 63, g = ln & 15;
      int k0 = (kt << 5) + ((ln >> 4) << 3);
      unsigned am = s_am[g * 10 + v];
      f16x8 pk;
      if (k0 + 8 <= HS) {
        float a0 = 0.f, a1 = 0.f, a2 = 0.f, a3 = 0.f;
        float a4 = 0.f, a5 = 0.f, a6 = 0.f, a7 = 0.f;
        for (int u = 0; u < v; ++u) {
          float mf = (float)((am >> u) & 1u);
          f16x8 hh = *(const f16x8*)(sGhist + (u * 16 + g) * 304 + k0);
          a0 += mf * (float)hh[0]; a1 += mf * (float)hh[1];
          a2 += mf * (float)hh[2]; a3 += mf * (float)hh[3];
          a4 += mf * (float)hh[4]; a5 += mf * (float)hh[5];
          a6 += mf * (float)hh[6]; a7 += mf * (float)hh[7];
        }
        pk[0] = (_Float16)a0; pk[1] = (_Float16)a1;
        pk[2] = (_Float16)a2; pk[3] = (_Float16)a3;
        pk[4] = (_Float16)a4; pk[5] = (_Float16)a5;
        pk[6] = (_Float16)a6; pk[7] = (_Float16)a7;
      } else {
        int t = s_t[g * 10 + v], p = s_p[g * 10 + v];
        #pragma unroll
        for (int e = 0; e < 8; ++e) {
          int k = k0 + e;
          float x = 0.f;
          if (k < HS) {
            for (int u = 0; u < v; ++u) {
              float mf = (float)((am >> u) & 1u);
              x += mf * (float)sGhist[(u * 16 + g) * 304 + k];
            }
          } else if (k < 327) x = (k - 301 == t) ? 1.f : 0.f;
          else if (k < 336)   x = (k - 327 == p) ? 1.f : 0.f;
          else if (k == 336)  x = 1.f;
          pk[e] = (_Float16)x;
        }
      }
      *(f16x8*)(sAf1 + c * 16) = pk;
    }
    for (int i = tid; i < 16 * 19; i += NTH) {
      int g = i / 19, kk = 301 + i % 19;
      float val = (kk < 310) ? ((kk - 301 == s_p[g * 10 + v]) ? 1.f : 0.f)
                             : ((kk == 310) ? 1.f : 0.f);
      *(_Float16*)(sAf2 + fragOff(g, kk)) = (_Float16)val;
    }
    BAR();

    // ---------- GRU stream: 55 kt-groups, LDS ring, counted vmcnt ----------
    {
      f32x4 z = {0.f, 0.f, 0.f, 0.f};
      f32x4 aA0 = z, aA1 = z, aA2 = z, aB0 = z, aB1 = z, aB2 = z;
      f32x4 aC0 = z, aC1 = z, aC2 = z, aD0 = z, aD1 = z, aD2 = z;
      f32x4 aE0 = z, aE1 = z, aE2 = z;
      G_T11(aA0, aA1, aA2, 0)
      G_T11(aB0, aB1, aB2, 11)
      G_T11(aC0, aC1, aC2, 22)
      G_T11(aD0, aD1, aD2, 33)
      G_T11L(aE0, aE1, aE2, 44)
      // batched epilogue (WnX global loads AFTER stream drained)
      GRU_EPI(0, aA0, aA1, aA2)
      GRU_EPI(1, aB0, aB1, aB2)
      GRU_EPI(2, aC0, aC1, aC2)
      GRU_EPI(3, aD0, aD1, aD2)
      GRU_EPI(4, aE0, aE1, aE2)
    }
    // gate prologue flies through the mid barrier (skip on last step:
    // nothing must be outstanding when the v-loop exits)
    if (v < nmax - 1) { Q_ISS(0) Q_ISS(1) Q_ISS(2) }
    BAR();

    // ---------- gate/mapper stream ----------
    if (v < nmax - 1) {
      f32x4 z = {0.f, 0.f, 0.f, 0.f};
      f32x4 cA0 = z, cA1 = z, cB0 = z, cB1 = z, cC0 = z, cC1 = z;
      f32x4 cD0 = z, cD1 = z, cE0 = z, cE1 = z;
      Q_T10(cA0, cA1, 0)
      Q_T10(cB0, cB1, 10)
      Q_T10(cC0, cC1, 20)
      Q_T10(cD0, cD1, 30)
      Q_T10L(cE0, cE1, 40)
      GATE_EPI(0, cA0, cA1)
      GATE_EPI(1, cB0, cB1)
      GATE_EPI(2, cC0, cC1)
      GATE_EPI(3, cD0, cD1)
      GATE_EPI(4, cE0, cE1)
      // next step's GRU prologue flies through the end barrier + phase A
      G_ISS(0) G_ISS(1) G_ISS(2)
    }
    BAR();
  }

  // ---------- df feature (overlaid on sStageC; no DMA outstanding) ----------
  if (tid < 16) {
    int g = tid;
    #pragma unroll
    for (int i2 = 0; i2 < 27; ++i2) s_df[g][i2] = 0.f;
    int n = s_n[g];
    int gi = s_gi[g];
    for (int vv = 0; vv < n; ++vv) {
      int p = s_p[g * 10 + vv];
      int base = gi * MAXN + vv;
      s_df[g][3 * p]     = rin[base];
      s_df[g][3 * p + 1] = cin[base];
      s_df[g][3 * p + 2] = gmin[base];
    }
  }
  __syncthreads();

  // ---------- df_enc ----------
  {
    int bb = tid >> 4, o = tid & 15;   // 256 threads = 16x16
    float a = b1[o];
    #pragma unroll
    for (int k = 0; k < 27; ++k) a = fmaf(W1[o * 27 + k], s_df[bb][k], a);
    s_hd[bb][o] = fmaxf(a, 0.f);
  }
  __syncthreads();
  if (tid < 128) {
    int bb = tid >> 3, o = tid & 7;
    float a = b2[o];
    #pragma unroll
    for (int k = 0; k < 16; ++k) a = fmaf(W2[o * 16 + k], s_hd[bb][k], a);
    s_hd2[bb][o] = a;
  }
  __syncthreads();

  // ---------- heads ----------
  if (tid < 2 * NZ) {
    bool ismu = tid < NZ;
    int oo = ismu ? tid : tid - NZ;
    const float* WT = ismu ? WmuT : WlvT;
    float acc[16];
    #pragma unroll
    for (int g = 0; g < 16; ++g) acc[g] = 0.f;
    for (int k0 = 0; k0 < 304; k0 += 8) {
      float wv[8];
      #pragma unroll
      for (int e = 0; e < 8; ++e) {
        int k = k0 + e;
        wv[e] = (k < HS) ? WT[k * NZ + oo] : 0.f;
      }
      #pragma unroll
      for (int g = 0; g < 16; ++g) {
        f16x8 hh = *(const f16x8*)(sHg + g * 304 + k0);
        #pragma unroll
        for (int e = 0; e < 8; ++e) acc[g] += wv[e] * (float)hh[e];
      }
    }
    #pragma unroll
    for (int g = 0; g < 16; ++g) {
      float a = acc[g];
      #pragma unroll
      for (int kk = 0; kk < 8; ++kk) a += WT[(HS + kk) * NZ + oo] * s_hd2[g][kk];
      a += ismu ? bmu[oo] : blv[oo];
      out[(ismu ? 0 : BSZ * NZ) + s_gi[g] * NZ + oo] = a;
    }
  }
}

extern "C" void kernel_launch(void* const* d_in, const int* in_sizes, int n_in,
                              void* d_out, int out_size, void* d_ws, size_t ws_size,
                              hipStream_t stream) {
  const int*   node_type = (const int*)d_in[0];
  const int*   pos       = (const int*)d_in[1];
  const int*   adj       = (const int*)d_in[2];
  const int*   vcount    = (const int*)d_in[3];
  const float* rin       = (const float*)d_in[4];
  const float* cin       = (const float*)d_in[5];
  const float* gmin      = (const float*)d_in[6];
  const float* Wih       = (const float*)d_in[7];
  const float* Whh       = (const float*)d_in[8];
  const float* b_ih      = (const float*)d_in[9];
  const float* b_hh      = (const float*)d_in[10];
  const float* Wg        = (const float*)d_in[11];
  const float* bg        = (const float*)d_in[12];
  const float* Wm        = (const float*)d_in[13];
  const float* W1        = (const float*)d_in[14];
  const float* b1        = (const float*)d_in[15];
  const float* W2        = (const float*)d_in[16];
  const float* b2        = (const float*)d_in[17];
  const float* Wmu       = (const float*)d_in[18];
  const float* bmu       = (const float*)d_in[19];
  const float* Wlv       = (const float*)d_in[20];
  const float* blv       = (const float*)d_in[21];

  // ws layout (bytes, all 16B-aligned)
  char* wsb = (char*)d_ws;
  unsigned short* B1 = (unsigned short*)wsb;              // 675,840 B
  unsigned short* B2 = (unsigned short*)(wsb + 675840);   // 409,600 B
  float* WnX  = (float*)(wsb + 1085440);                  // 44,800 B
  float* bn   = (float*)(wsb + 1130240);                  // 1,280 B
  float* WmuT = (float*)(wsb + 1131520);                  // 69,216 B
  float* WlvT = (float*)(wsb + 1200736);                  // 69,216 B
  int*   order = (int*)(wsb + 1269952);                   // 16,384 B

  ckt_prep<<<512, 256, 0, stream>>>(Wih, Whh, b_ih, b_hh, Wg, bg, Wm, Wmu, Wlv,
                                    B1, B2, WnX, bn, WmuT, WlvT);
  ckt_sort<<<1, 1024, 0, stream>>>(vcount, order);

  ckt_main<<<NBLK, NTH, 0, stream>>>(node_type, pos, adj, vcount, rin, cin, gmin,
      W1, b1, W2, b2, bmu, blv,
      (const char*)B1, (const char*)B2, WnX, bn, WmuT, WlvT, order, (float*)d_out);
}

// Round 15
// 366.060 us; speedup vs baseline: 2.8009x; 2.8009x over previous
//
#include <hip/hip_runtime.h>
#include <hip/hip_bf16.h>

// CktGNN encoder via MFMA. R15: forward-Hin accumulation (phase A eliminated)
// on the R11 substrate (best: 162us).
// Model from R10-R14: per-block B-stream rate ~24 B/cyc regardless of wave
// count; wall = 9 steps x 43k cyc. Cuts: (1) gate epilogue scatter-adds
// gated[v] into per-vertex fragment buffers sHinF[10] (one-hots prefilled
// once) -> no phase A, 2 barriers/step; (2) v=0 streams only kt9-10 (Hin=0);
// (3) per-block j-tile rotation (w+bx)%19 decorrelates L2 streams.
// R14 lesson: async DMA macro-streams explode VGPR via address hoisting; stay
// with register streaming (named depth-4, R11-proven).
//   GRU ext K=352: [Hin(301) | onehot_t(26) | onehot_p(9) | 1 | pad]
//   gate ext K=320: [H(301) | onehot_p(9) | 1 | pad]

#define HS 301
#define NVT 26
#define MAXPOS 9
#define MAXN 10
#define BSZ 4096
#define VS 310
#define GS 309
#define NZ 56

#define KT1 11          // GRU ext K tiles (K=352)
#define KT2 10          // gate ext K tiles (K=320)
#define NJT 19          // j tiles
#define NB1 (NJT*KT1*3*512)
#define NB2 (NJT*KT2*2*512)
#define VSZ 11264       // per-vertex A-frag buffer bytes (KT1*1024)

typedef _Float16 f16x8 __attribute__((ext_vector_type(8)));
typedef float f32x4 __attribute__((ext_vector_type(4)));

constexpr int NTH  = 1024;   // 16 waves
constexpr int BT   = 16;
constexpr int NBLK = 256;

__device__ __forceinline__ int fragOff(int g, int k) {
  return ((k >> 5) << 10) + ((((k & 31) >> 3) << 4) + g) * 16 + ((k & 7) << 1);
}
__device__ __forceinline__ float sigm(float x) { return 1.0f / (1.0f + __expf(-x)); }
__device__ __forceinline__ float tanh_fast(float x) {
  float e = __expf(2.0f * x);
  return 1.0f - 2.0f / (e + 1.0f);
}
#define BC(x) __builtin_bit_cast(f16x8, (x))
#define BAR() { asm volatile("s_waitcnt lgkmcnt(0)" ::: "memory"); \
                __builtin_amdgcn_s_barrier(); }

// ---------------- sort: counting sort graphs by depth n ----------------
__global__ void ckt_sort(const int* __restrict__ vcount, int* __restrict__ order) {
  __shared__ int cnt[12], off[12];
  int tid = threadIdx.x;
  if (tid < 12) cnt[tid] = 0;
  __syncthreads();
  for (int g = tid; g < BSZ; g += 1024) {
    int n = vcount[g]; n = n < 1 ? 1 : (n > MAXN ? MAXN : n);
    atomicAdd(&cnt[n], 1);
  }
  __syncthreads();
  if (tid == 0) {
    int s = 0;
    for (int i = 1; i <= MAXN; ++i) { off[i] = s; s += cnt[i]; }
  }
  __syncthreads();
  for (int g = tid; g < BSZ; g += 1024) {
    int n = vcount[g]; n = n < 1 ? 1 : (n > MAXN ? MAXN : n);
    int p = atomicAdd(&off[n], 1);
    order[p] = g;
  }
}

// ---------------- prep: pack weights into fragment order ----------------
__global__ void ckt_prep(const float* __restrict__ Wih, const float* __restrict__ Whh,
                         const float* __restrict__ b_ih, const float* __restrict__ b_hh,
                         const float* __restrict__ Wg,  const float* __restrict__ bg,
                         const float* __restrict__ Wm,
                         const float* __restrict__ Wmu, const float* __restrict__ Wlv,
                         unsigned short* __restrict__ B1, unsigned short* __restrict__ B2,
                         float* __restrict__ WnX, float* __restrict__ bn,
                         float* __restrict__ WmuT, float* __restrict__ WlvT)
{
  int i0 = blockIdx.x * blockDim.x + threadIdx.x;
  int str = gridDim.x * blockDim.x;
  // B1: [jt][kt][g3][lane][ii]
  for (int i = i0; i < NB1; i += str) {
    int ii = i & 7, lane = (i >> 3) & 63;
    int r = i >> 9;
    int g3 = r % 3; r /= 3;
    int kt = r % KT1; int jt = r / KT1;
    int j = jt * 16 + (lane & 15);
    int k = kt * 32 + ((lane >> 4) << 3) + ii;
    float val = 0.f;
    if (j < HS) {
      int row = g3 * HS + j;
      if (k < HS) val = Whh[row * HS + k];
      else if (k == 336) val = (g3 < 2) ? (b_ih[row] + b_hh[row]) : b_hh[row];
      else if (g3 < 2) {
        if (k < 327)      val = Wih[row * 35 + (k - 301)];
        else if (k < 336) val = Wih[row * 35 + 26 + (k - 327)];
      }
    }
    B1[i] = __builtin_bit_cast(unsigned short, (_Float16)val);
  }
  // B2: [jt][kt][gm][lane][ii]
  for (int i = i0; i < NB2; i += str) {
    int ii = i & 7, lane = (i >> 3) & 63;
    int r = i >> 9;
    int gm = r % 2; r /= 2;
    int kt = r % KT2; int jt = r / KT2;
    int j = jt * 16 + (lane & 15);
    int k = kt * 32 + ((lane >> 4) << 3) + ii;
    float val = 0.f;
    if (j < HS) {
      const float* W = gm ? Wm : Wg;
      if (k < HS)       val = W[j * VS + k];
      else if (k < 310) val = W[j * VS + HS + (k - 301)];
      else if (k == 310) val = gm ? 0.f : bg[j];
    }
    B2[i] = __builtin_bit_cast(unsigned short, (_Float16)val);
  }
  for (int i = i0; i < 35 * 320; i += str) {
    int x = i / 320, j = i % 320;
    WnX[i] = (j < HS) ? Wih[(2 * HS + j) * 35 + x] : 0.f;
  }
  for (int i = i0; i < 320; i += str) bn[i] = (i < HS) ? b_ih[2 * HS + i] : 0.f;
  for (int i = i0; i < GS * NZ; i += str) {
    int k = i / NZ, o = i % NZ;
    WmuT[i] = Wmu[o * GS + k];
    WlvT[i] = Wlv[o * GS + k];
  }
}

// ---------------- main ----------------
__global__ __launch_bounds__(NTH) void ckt_main(
    const int* __restrict__ node_type, const int* __restrict__ pos,
    const int* __restrict__ adj, const int* __restrict__ vcount,
    const float* __restrict__ rin, const float* __restrict__ cin,
    const float* __restrict__ gmin,
    const float* __restrict__ W1, const float* __restrict__ b1,
    const float* __restrict__ W2, const float* __restrict__ b2,
    const float* __restrict__ bmu, const float* __restrict__ blv,
    const uint4* __restrict__ B1, const uint4* __restrict__ B2,
    const float* __restrict__ WnX, const float* __restrict__ bnG,
    const float* __restrict__ WmuT, const float* __restrict__ WlvT,
    const int* __restrict__ order,
    float* __restrict__ out)
{
  __shared__ __align__(16) char sHinF[10 * VSZ];     // per-vertex A-frags, 110 KB
  __shared__ __align__(16) char sAf2[KT2 * 1024];    // gate A-frags, 10 KB
  __shared__ __align__(16) _Float16 sHg[16 * 304];   // graph state, 9.5 KB
  __shared__ float sBn[320];
  __shared__ int s_gi[16];
  __shared__ int s_t[160], s_p[160], s_n[16];
  __shared__ unsigned s_fm[160];                     // forward successor masks
  __shared__ int s_nmax;
  __shared__ float s_df[16][28];
  __shared__ float s_hd[16][16];
  __shared__ float s_hd2[16][8];

  const int tid  = threadIdx.x;
  const int bx   = (int)blockIdx.x;
  const int b0   = bx * BT;
  const int w    = tid >> 6;          // 0..15
  const int lane = tid & 63;

  if (tid < 16) s_gi[tid] = order[b0 + tid];
  __syncthreads();
  if (tid < 16) {
    int n = vcount[s_gi[tid]];
    s_n[tid] = n < 1 ? 1 : (n > MAXN ? MAXN : n);
    sHg[tid * 304 + 301] = (_Float16)0.f;   // zero f16 pad (heads read f16x8)
    sHg[tid * 304 + 302] = (_Float16)0.f;
    sHg[tid * 304 + 303] = (_Float16)0.f;
  }
  if (tid < 160) {
    int g = tid / 10, vv = tid % 10;
    s_t[tid] = node_type[s_gi[g] * MAXN + vv];
    s_p[tid] = pos[s_gi[g] * MAXN + vv];
  }
  if (tid < 320) sBn[tid] = bnG[tid];
  __syncthreads();
  // forward masks: fm[g][u] = bits vv>u (vv<n) with edge u->vv
  if (tid < 160) {
    int g = tid / 10, u = tid % 10;
    unsigned m = 0;
    int n = s_n[g];
    if (u < n) {
      for (int vv = u + 1; vv < n; ++vv)
        if (adj[s_gi[g] * 100 + u * 10 + vv]) m |= (1u << vv);
    }
    s_fm[tid] = m;
  }
  if (tid == 0) {
    int mx = 1;
    for (int g = 0; g < 16; ++g) mx = max(mx, s_n[g]);
    s_nmax = mx;
  }
  // prefill every vertex's A-frag buffer: Hin region = 0, one-hots + const
  for (int c = tid; c < 10 * KT1 * 64; c += NTH) {
    int vv = c / (KT1 * 64), cc = c % (KT1 * 64);
    int kt = cc >> 6, ln = cc & 63, g = ln & 15;
    int k0 = (kt << 5) + ((ln >> 4) << 3);
    int t = s_t[g * 10 + vv], p = s_p[g * 10 + vv];
    f16x8 pk;
    #pragma unroll
    for (int e = 0; e < 8; ++e) {
      int k = k0 + e;
      float x = 0.f;
      if (k >= 301 && k < 327)      x = (k - 301 == t) ? 1.f : 0.f;
      else if (k >= 327 && k < 336) x = (k - 327 == p) ? 1.f : 0.f;
      else if (k == 336)            x = 1.f;
      pk[e] = (_Float16)x;
    }
    *(f16x8*)(sHinF + vv * VSZ + cc * 16) = pk;
  }
  __syncthreads();
  const int nmax = s_nmax;

  const int lq4 = (lane >> 4) << 2;   // base graph row of this lane's D rows
  const int jc  = lane & 15;          // column-within-tile
  // per-block j-tile rotation: decorrelate L2 address streams across blocks
  const int jt1 = (w + bx) % NJT;
  const int jt2 = (w + 16 + bx) % NJT;   // used if w < 3

#define LB1(P0, P1, P2, KT) \
    P0 = BC(Bp[((KT) * 3 + 0) * 64]); \
    P1 = BC(Bp[((KT) * 3 + 1) * 64]); \
    P2 = BC(Bp[((KT) * 3 + 2) * 64]);
#define ST1(P0, P1, P2, KT, KTN) { \
    f16x8 av = *(const f16x8*)(afv + ((KT) << 10) + (lane << 4)); \
    f16x8 c0 = P0, c1 = P1, c2 = P2; \
    LB1(P0, P1, P2, KTN) \
    a0 = __builtin_amdgcn_mfma_f32_16x16x32_f16(av, c0, a0, 0, 0, 0); \
    a1 = __builtin_amdgcn_mfma_f32_16x16x32_f16(av, c1, a1, 0, 0, 0); \
    a2 = __builtin_amdgcn_mfma_f32_16x16x32_f16(av, c2, a2, 0, 0, 0); }
#define ST1E(P0, P1, P2, KT) { \
    f16x8 av = *(const f16x8*)(afv + ((KT) << 10) + (lane << 4)); \
    a0 = __builtin_amdgcn_mfma_f32_16x16x32_f16(av, P0, a0, 0, 0, 0); \
    a1 = __builtin_amdgcn_mfma_f32_16x16x32_f16(av, P1, a1, 0, 0, 0); \
    a2 = __builtin_amdgcn_mfma_f32_16x16x32_f16(av, P2, a2, 0, 0, 0); }
#define GRU_EPI(JT) { \
    int j = (JT) * 16 + jc; \
    bool jv = j < HS; \
    _Pragma("unroll") \
    for (int q = 0; q < 4; ++q) { \
      int g = lq4 + q; \
      float inn = 0.f; \
      if (jv) { \
        int t = s_t[g * 10 + v], p = s_p[g * 10 + v]; \
        inn = sBn[j] + WnX[t * 320 + j] + WnX[(26 + p) * 320 + j]; \
      } \
      float rg = sigm(a0[q]); \
      float zg = sigm(a1[q]); \
      float ng = tanh_fast(inn + rg * a2[q]); \
      float hinv = jv ? (float)*(const _Float16*)(afv + fragOff(g, j)) : 0.f; \
      float hv = (1.f - zg) * ng + zg * hinv; \
      float hval = (v < s_n[g]) ? hv : 0.f; \
      if (jv) { \
        *(_Float16*)(sAf2 + fragOff(g, j)) = (_Float16)hval; \
        if (v == s_n[g] - 1) sHg[g * 304 + j] = (_Float16)hv; \
      } \
    } }
#define GRU_TILE_FULL(JT) { \
    const uint4* Bp = B1 + (size_t)(JT) * (KT1 * 3 * 64) + lane; \
    f16x8 p00, p01, p02, p10, p11, p12, p20, p21, p22, p30, p31, p32; \
    LB1(p00, p01, p02, 0) LB1(p10, p11, p12, 1) \
    LB1(p20, p21, p22, 2) LB1(p30, p31, p32, 3) \
    f32x4 a0 = {0.f, 0.f, 0.f, 0.f}, a1 = a0, a2 = a0; \
    ST1(p00, p01, p02, 0, 4) ST1(p10, p11, p12, 1, 5) \
    ST1(p20, p21, p22, 2, 6) ST1(p30, p31, p32, 3, 7) \
    ST1(p00, p01, p02, 4, 8) ST1(p10, p11, p12, 5, 9) \
    ST1(p20, p21, p22, 6, 10) \
    ST1E(p30, p31, p32, 7) ST1E(p00, p01, p02, 8) \
    ST1E(p10, p11, p12, 9) ST1E(p20, p21, p22, 10) \
    GRU_EPI(JT) }
#define GRU_TILE_V0(JT) { \
    const uint4* Bp = B1 + (size_t)(JT) * (KT1 * 3 * 64) + lane; \
    f16x8 p00, p01, p02, p10, p11, p12; \
    LB1(p00, p01, p02, 9) LB1(p10, p11, p12, 10) \
    f32x4 a0 = {0.f, 0.f, 0.f, 0.f}, a1 = a0, a2 = a0; \
    ST1E(p00, p01, p02, 9) ST1E(p10, p11, p12, 10) \
    GRU_EPI(JT) }

#define LB2(P0, P1, KT) \
    P0 = BC(Bp[((KT) * 2 + 0) * 64]); \
    P1 = BC(Bp[((KT) * 2 + 1) * 64]);
#define ST2(P0, P1, KT, KTN) { \
    f16x8 av = *(const f16x8*)(sAf2 + ((KT) << 10) + (lane << 4)); \
    f16x8 d0 = P0, d1 = P1; \
    LB2(P0, P1, KTN) \
    c0 = __builtin_amdgcn_mfma_f32_16x16x32_f16(av, d0, c0, 0, 0, 0); \
    c1 = __builtin_amdgcn_mfma_f32_16x16x32_f16(av, d1, c1, 0, 0, 0); }
#define ST2E(P0, P1, KT) { \
    f16x8 av = *(const f16x8*)(sAf2 + ((KT) << 10) + (lane << 4)); \
    c0 = __builtin_amdgcn_mfma_f32_16x16x32_f16(av, P0, c0, 0, 0, 0); \
    c1 = __builtin_amdgcn_mfma_f32_16x16x32_f16(av, P1, c1, 0, 0, 0); }
// scatter-add gated[v] into future vertices' Hin fragments
#define GATE_SCAT(JT) { \
    int j = (JT) * 16 + jc; \
    if (j < HS) { \
      _Pragma("unroll") \
      for (int q = 0; q < 4; ++q) { \
        int g = lq4 + q; \
        float val = sigm(c0[q]) * c1[q]; \
        unsigned m = s_fm[g * 10 + v]; \
        while (m) { \
          int vv = __builtin_ctz(m); m &= m - 1; \
          _Float16* ap = (_Float16*)(sHinF + vv * VSZ + fragOff(g, j)); \
          *ap = (_Float16)((float)*ap + val); \
        } \
      } \
    } }
#define GATE_TILE(JT) { \
    const uint4* Bp = B2 + (size_t)(JT) * (KT2 * 2 * 64) + lane; \
    f16x8 q00, q01, q10, q11, q20, q21, q30, q31; \
    LB2(q00, q01, 0) LB2(q10, q11, 1) LB2(q20, q21, 2) LB2(q30, q31, 3) \
    f32x4 c0 = {0.f, 0.f, 0.f, 0.f}, c1 = c0; \
    ST2(q00, q01, 0, 4) ST2(q10, q11, 1, 5) ST2(q20, q21, 2, 6) \
    ST2(q30, q31, 3, 7) ST2(q00, q01, 4, 8) ST2(q10, q11, 5, 9) \
    ST2E(q20, q21, 6) ST2E(q30, q31, 7) ST2E(q00, q01, 8) ST2E(q10, q11, 9) \
    GATE_SCAT(JT) }

  for (int v = 0; v < nmax; ++v) {
    const char* afv = sHinF + v * VSZ;
    // ---------- GRU: stream B1 vs sHinF[v]; v=0 needs only kt9-10 ----------
    if (v == 0) {
      GRU_TILE_V0(jt1)
      if (w < 3) GRU_TILE_V0(jt2)
    } else {
      GRU_TILE_FULL(jt1)
      if (w < 3) GRU_TILE_FULL(jt2)
    }
    // gate A-frag one-hot region for vertex v (k=301..319)
    if (tid < 16 * 19) {
      int g = tid / 19, kk = 301 + tid % 19;
      float val = (kk < 310) ? ((kk - 301 == s_p[g * 10 + v]) ? 1.f : 0.f)
                             : ((kk == 310) ? 1.f : 0.f);
      *(_Float16*)(sAf2 + fragOff(g, kk)) = (_Float16)val;
    }
    BAR();

    // ---------- gate/mapper: stream B2 vs sAf2, scatter into sHinF ----------
    if (v < nmax - 1) {
      GATE_TILE(jt1)
      if (w < 3) GATE_TILE(jt2)
    }
    BAR();
  }

  // ---------- df feature ----------
  if (tid < 16) {
    int g = tid;
    #pragma unroll
    for (int i2 = 0; i2 < 27; ++i2) s_df[g][i2] = 0.f;
    int n = s_n[g];
    int gi = s_gi[g];
    for (int vv = 0; vv < n; ++vv) {
      int p = s_p[g * 10 + vv];
      int base = gi * MAXN + vv;
      s_df[g][3 * p]     = rin[base];
      s_df[g][3 * p + 1] = cin[base];
      s_df[g][3 * p + 2] = gmin[base];
    }
  }
  __syncthreads();

  // ---------- df_enc ----------
  if (tid < 256) {
    int bb = tid >> 4, o = tid & 15;   // 16x16
    float a = b1[o];
    #pragma unroll
    for (int k = 0; k < 27; ++k) a = fmaf(W1[o * 27 + k], s_df[bb][k], a);
    s_hd[bb][o] = fmaxf(a, 0.f);
  }
  __syncthreads();
  if (tid < 128) {
    int bb = tid >> 3, o = tid & 7;
    float a = b2[o];
    #pragma unroll
    for (int k = 0; k < 16; ++k) a = fmaf(W2[o * 16 + k], s_hd[bb][k], a);
    s_hd2[bb][o] = a;
  }
  __syncthreads();

  // ---------- heads ----------
  if (tid < 2 * NZ) {
    bool ismu = tid < NZ;
    int oo = ismu ? tid : tid - NZ;
    const float* WT = ismu ? WmuT : WlvT;
    float acc[16];
    #pragma unroll
    for (int g = 0; g < 16; ++g) acc[g] = 0.f;
    for (int k0 = 0; k0 < 304; k0 += 8) {
      float wv[8];
      #pragma unroll
      for (int e = 0; e < 8; ++e) {
        int k = k0 + e;
        wv[e] = (k < HS) ? WT[k * NZ + oo] : 0.f;
      }
      #pragma unroll
      for (int g = 0; g < 16; ++g) {
        f16x8 hh = *(const f16x8*)(sHg + g * 304 + k0);
        #pragma unroll
        for (int e = 0; e < 8; ++e) acc[g] += wv[e] * (float)hh[e];
      }
    }
    #pragma unroll
    for (int g = 0; g < 16; ++g) {
      float a = acc[g];
      #pragma unroll
      for (int kk = 0; kk < 8; ++kk) a += WT[(HS + kk) * NZ + oo] * s_hd2[g][kk];
      a += ismu ? bmu[oo] : blv[oo];
      out[(ismu ? 0 : BSZ * NZ) + s_gi[g] * NZ + oo] = a;
    }
  }
}

extern "C" void kernel_launch(void* const* d_in, const int* in_sizes, int n_in,
                              void* d_out, int out_size, void* d_ws, size_t ws_size,
                              hipStream_t stream) {
  const int*   node_type = (const int*)d_in[0];
  const int*   pos       = (const int*)d_in[1];
  const int*   adj       = (const int*)d_in[2];
  const int*   vcount    = (const int*)d_in[3];
  const float* rin       = (const float*)d_in[4];
  const float* cin       = (const float*)d_in[5];
  const float* gmin      = (const float*)d_in[6];
  const float* Wih       = (const float*)d_in[7];
  const float* Whh       = (const float*)d_in[8];
  const float* b_ih      = (const float*)d_in[9];
  const float* b_hh      = (const float*)d_in[10];
  const float* Wg        = (const float*)d_in[11];
  const float* bg        = (const float*)d_in[12];
  const float* Wm        = (const float*)d_in[13];
  const float* W1        = (const float*)d_in[14];
  const float* b1        = (const float*)d_in[15];
  const float* W2        = (const float*)d_in[16];
  const float* b2        = (const float*)d_in[17];
  const float* Wmu       = (const float*)d_in[18];
  const float* bmu       = (const float*)d_in[19];
  const float* Wlv       = (const float*)d_in[20];
  const float* blv       = (const float*)d_in[21];

  // ws layout (bytes, all 16B-aligned)
  char* wsb = (char*)d_ws;
  unsigned short* B1 = (unsigned short*)wsb;              // 642,048 B
  unsigned short* B2 = (unsigned short*)(wsb + 642048);   // 389,120 B
  float* WnX  = (float*)(wsb + 1031168);                  // 44,800 B
  float* bn   = (float*)(wsb + 1075968);                  // 1,280 B
  float* WmuT = (float*)(wsb + 1077248);                  // 69,216 B
  float* WlvT = (float*)(wsb + 1146464);                  // 69,216 B
  int*   order = (int*)(wsb + 1215680);                   // 16,384 B

  ckt_prep<<<512, 256, 0, stream>>>(Wih, Whh, b_ih, b_hh, Wg, bg, Wm, Wmu, Wlv,
                                    B1, B2, WnX, bn, WmuT, WlvT);
  ckt_sort<<<1, 1024, 0, stream>>>(vcount, order);

  ckt_main<<<NBLK, NTH, 0, stream>>>(node_type, pos, adj, vcount, rin, cin, gmin,
      W1, b1, W2, b2, bmu, blv,
      (const uint4*)B1, (const uint4*)B2, WnX, bn, WmuT, WlvT, order, (float*)d_out);
}